// Round 3
// baseline (336.051 us; speedup 1.0000x reference)
//
#include <hip/hip_runtime.h>
#include <hip/hip_bf16.h>
#include <math.h>

#define MAXN 0.996f          /* (1 - 4e-3) / sqrt(c) */
#define MINN 1e-15f
#define ATEPS (1.0f - 1e-7f)

typedef unsigned short u16;
typedef __attribute__((ext_vector_type(8))) short bf16x8;
typedef __attribute__((ext_vector_type(16))) float fx16;

__device__ __forceinline__ u16 f2bf(float v) {
  union { __hip_bfloat16 b; u16 u; } cv; cv.b = __float2bfloat16(v); return cv.u;
}
__device__ __forceinline__ float bf2f(u16 u) {
  union { u16 u; __hip_bfloat16 b; } cv; cv.u = u; return __bfloat162float(cv.b);
}

// ---- split W into hi/lo bf16 planes ----
__global__ void cvtW(const float* __restrict__ W1, const float* __restrict__ W2,
                     u16* __restrict__ w1h, u16* __restrict__ w1l,
                     u16* __restrict__ w2h, u16* __restrict__ w2l) {
  int idx = blockIdx.x * 512 + threadIdx.x;
  if (idx < 512 * 256) {
    float v = W1[idx];
    u16 h = f2bf(v);
    w1h[idx] = h; w1l[idx] = f2bf(v - bf2f(h));
  } else {
    int j = idx - 512 * 256;   // < 128*512
    float v = W2[j];
    u16 h = f2bf(v);
    w2h[j] = h; w2l[j] = f2bf(v - bf2f(h));
  }
}

// LDS k-blocked layout for x/h: group g = k>>3 ; byte = g*2048 + m*16 + (k&7)*2
// (128 m rows * 8 k * 2B = 2048 B per group). All GEMM reads/writes are
// conflict-free: lanes differ in m -> consecutive 16B slots.

__global__ __launch_bounds__(1024, 4) void hyper(
    const float* __restrict__ X,    // [B,256]
    const float* __restrict__ b1,   // [512]
    const float* __restrict__ b2,   // [128]
    const u16* __restrict__ w1h, const u16* __restrict__ w1l,   // [512,256]
    const u16* __restrict__ w2h, const u16* __restrict__ w2l,   // [128,512]
    float* __restrict__ out)        // [B,128]
{
  // [0,131072): x hi (0..64K) + x lo (64K..128K)  ->  h [64 groups][128][8] bf16
  //                                               ->  out f32 [128][128] (0..64K)
  __shared__ __align__(16) char smem[142384];
  float* xnl  = (float*)(smem + 131072);          // [128]
  float* b1s  = (float*)(smem + 131584);          // [512]
  float* b2s  = (float*)(smem + 133632);          // [128]
  float* red1 = (float*)(smem + 134144);          // [4][128]
  float* red2 = (float*)(smem + 136192);
  float* red3 = (float*)(smem + 138240);
  float* red4 = (float*)(smem + 140288);
  float* bno  = (float*)(smem + 142336);          // [10]
  float* sy   = (float*)(smem + 142376);          // [2]

  const int t = threadIdx.x;
  const int w = t >> 6, l = t & 63, l31 = l & 31, hi = l >> 5;
  const int q = w & 3, bq = w >> 2;               // n-quarter, batch-quarter
  const int mL = bq * 32 + l31;                   // this lane's batch row (GEMM phases)
  const long rowBase = (long)blockIdx.x * 128;

  // ================= phase 0: x -> LDS hi/lo (k-blocked), xn; b1/b2 stage =================
  {
    const int m0 = t >> 3, sub = t & 7;
    const float* xg = X + (rowBase + m0) * 256;
    float ss = 0.f;
#pragma unroll
    for (int j = 0; j < 8; j++) {
      float4 v = *(const float4*)(xg + (sub + j * 8) * 4);
      ss += v.x*v.x + v.y*v.y + v.z*v.z + v.w*v.w;
      u16 h0 = f2bf(v.x), h1 = f2bf(v.y), h2 = f2bf(v.z), h3 = f2bf(v.w);
      short4 sh; sh.x = (short)h0; sh.y = (short)h1; sh.z = (short)h2; sh.w = (short)h3;
      short4 sl;
      sl.x = (short)f2bf(v.x - bf2f(h0)); sl.y = (short)f2bf(v.y - bf2f(h1));
      sl.z = (short)f2bf(v.z - bf2f(h2)); sl.w = (short)f2bf(v.w - bf2f(h3));
      int c4 = sub + j * 8;                       // float4-quad index in row (k = c4*4)
      int byt = (c4 >> 1) * 2048 + m0 * 16 + (c4 & 1) * 8;
      *(short4*)(smem + byt) = sh;
      *(short4*)(smem + 65536 + byt) = sl;
    }
    ss += __shfl_xor(ss, 1); ss += __shfl_xor(ss, 2); ss += __shfl_xor(ss, 4);
    if (sub == 0) xnl[m0] = sqrtf(ss);

    float bv = 0.f;
    if (t < 512) { bv = b1[t]; b1s[t] = bv; }
    float s1 = bv * bv;
    s1 += __shfl_xor(s1, 1); s1 += __shfl_xor(s1, 2); s1 += __shfl_xor(s1, 4);
    s1 += __shfl_xor(s1, 8); s1 += __shfl_xor(s1, 16); s1 += __shfl_xor(s1, 32);
    if (t < 512 && l == 0) bno[w] = s1;
    float cv2 = 0.f;
    if (t < 128) { cv2 = b2[t]; b2s[t] = cv2; }
    float s2 = cv2 * cv2;
    s2 += __shfl_xor(s2, 1); s2 += __shfl_xor(s2, 2); s2 += __shfl_xor(s2, 4);
    s2 += __shfl_xor(s2, 8); s2 += __shfl_xor(s2, 16); s2 += __shfl_xor(s2, 32);
    if (t < 128 && l == 0) bno[8 + w] = s2;
  }
  __syncthreads();                                // B1
  if (t == 0) {
    float a = 0.f;
#pragma unroll
    for (int j = 0; j < 8; j++) a += bno[j];
    sy[0] = a;
  }
  if (t == 64) sy[1] = bno[8] + bno[9];

  // ================= GEMM1 (swapped): C = W1 . x^T  -> lane holds batch mL =================
  fx16 acc[4];
#pragma unroll
  for (int nt = 0; nt < 4; nt++)
#pragma unroll
    for (int r = 0; r < 16; r++) acc[nt][r] = 0.f;

  int woff[4];
#pragma unroll
  for (int nt = 0; nt < 4; nt++) woff[nt] = (q * 128 + nt * 32 + l31) * 256 + hi * 8;
  const char* xbh = smem + mL * 16 + hi * 2048;

#pragma unroll
  for (int kt = 0; kt < 16; kt++) {
    bf16x8 bh = *(const bf16x8*)(xbh + kt * 4096);
    bf16x8 bl = *(const bf16x8*)(xbh + 65536 + kt * 4096);
#pragma unroll
    for (int nt = 0; nt < 4; nt++) {
      bf16x8 wh = *(const bf16x8*)(const void*)(w1h + woff[nt] + kt * 16);
      bf16x8 wl = *(const bf16x8*)(const void*)(w1l + woff[nt] + kt * 16);
      acc[nt] = __builtin_amdgcn_mfma_f32_32x32x16_bf16(wh, bh, acc[nt], 0, 0, 0);
      acc[nt] = __builtin_amdgcn_mfma_f32_32x32x16_bf16(wh, bl, acc[nt], 0, 0, 0);
      acc[nt] = __builtin_amdgcn_mfma_f32_32x32x16_bf16(wl, bh, acc[nt], 0, 0, 0);
    }
  }

  // ================= layer-1 epilogue (all lane-local; 4-way cross-wave combines) ======
  float xn2;
  {
    float p = 0.f;
#pragma unroll
    for (int nt = 0; nt < 4; nt++)
#pragma unroll
      for (int r = 0; r < 16; r++) p += acc[nt][r] * acc[nt][r];
    p += __shfl_xor(p, 32);
    if (l < 32) red1[q * 128 + mL] = p;
  }
  __syncthreads();                                // B2
  {
    float s2 = red1[mL] + red1[128 + mL] + red1[256 + mL] + red1[384 + mL];
    float xnv = fmaxf(xnl[mL], MINN);
    float mxn = fmaxf(sqrtf(s2), MINN);
    float tv  = tanhf(mxn / xnv * atanhf(fminf(xnv, ATEPS)));
    float sc  = tv / mxn;
    float hn  = fmaxf(tv, MINN);
    if (hn > MAXN) { sc *= MAXN / hn; hn = MAXN; }
#pragma unroll
    for (int nt = 0; nt < 4; nt++)
#pragma unroll
      for (int r = 0; r < 16; r++) acc[nt][r] *= sc;
    // xy = <h, b1>
    float p = 0.f;
#pragma unroll
    for (int nt = 0; nt < 4; nt++)
#pragma unroll
      for (int qq = 0; qq < 4; qq++) {
        float4 bv = *(const float4*)(b1s + q * 128 + nt * 32 + qq * 8 + hi * 4);
        p += acc[nt][qq*4+0]*bv.x + acc[nt][qq*4+1]*bv.y + acc[nt][qq*4+2]*bv.z + acc[nt][qq*4+3]*bv.w;
      }
    p += __shfl_xor(p, 32);
    if (l < 32) red2[q * 128 + mL] = p;
    red4[0] = hn;  // dummy to keep hn? no -- keep in reg:
    // (hn kept live below via x2)
    float xy_dummy = 0.f; (void)xy_dummy;
    // stash hn in xn2 temporarily (real xn2 set later)
    xn2 = hn;
  }
  __syncthreads();                                // B3
  {
    float hn = xn2;
    float xy = red2[mL] + red2[128 + mL] + red2[256 + mL] + red2[384 + mL];
    float y2 = sy[0];
    float x2 = hn * hn;
    float A  = 1.f + 2.f * xy + y2;
    float Bc = 1.f - x2;
    float den = fmaxf(1.f + 2.f * xy + x2 * y2, MINN);
    float Ai = A / den, Bi = Bc / den;
    float p = 0.f;
#pragma unroll
    for (int nt = 0; nt < 4; nt++)
#pragma unroll
      for (int qq = 0; qq < 4; qq++) {
        float4 bv = *(const float4*)(b1s + q * 128 + nt * 32 + qq * 8 + hi * 4);
        float g0 = Ai * acc[nt][qq*4+0] + Bi * bv.x;
        float g1 = Ai * acc[nt][qq*4+1] + Bi * bv.y;
        float g2 = Ai * acc[nt][qq*4+2] + Bi * bv.z;
        float g3 = Ai * acc[nt][qq*4+3] + Bi * bv.w;
        acc[nt][qq*4+0] = g0; acc[nt][qq*4+1] = g1;
        acc[nt][qq*4+2] = g2; acc[nt][qq*4+3] = g3;
        p += g0*g0 + g1*g1 + g2*g2 + g3*g3;
      }
    p += __shfl_xor(p, 32);
    if (l < 32) red3[q * 128 + mL] = p;
  }
  __syncthreads();                                // B4
  {
    float g2 = red3[mL] + red3[128 + mL] + red3[256 + mL] + red3[384 + mL];
    float gn = fmaxf(sqrtf(g2), MINN);
    float pf = (gn > MAXN) ? (MAXN / gn) : 1.f;
    float gnp = fminf(gn, MAXN);
    float csc = pf * atanhf(fminf(gnp, ATEPS)) / gnp;
    float p = 0.f;
#pragma unroll
    for (int nt = 0; nt < 4; nt++)
#pragma unroll
      for (int r = 0; r < 16; r++) {
        float tvv = tanhf(csc * acc[nt][r]);
        acc[nt][r] = tvv;
        p += tvv * tvv;
      }
    p += __shfl_xor(p, 32);
    if (l < 32) red4[q * 128 + mL] = p;
  }
  __syncthreads();                                // B5
  {
    float t2 = red4[mL] + red4[128 + mL] + red4[256 + mL] + red4[384 + mL];
    float tn = fmaxf(sqrtf(t2), MINN);
    float tv2 = tanhf(tn);
    float sc4 = tv2 / tn;
    float on = tv2;
    if (on > MAXN) { sc4 *= MAXN / on; on = MAXN; }
    xn2 = fmaxf(on, MINN);
#pragma unroll
    for (int nt = 0; nt < 4; nt++)
#pragma unroll
      for (int r = 0; r < 16; r++) acc[nt][r] *= sc4;
  }
  // h -> LDS bf16 (k-blocked), overlays dead x region
#pragma unroll
  for (int nt = 0; nt < 4; nt++)
#pragma unroll
    for (int qq = 0; qq < 4; qq++) {
      short4 sh;
      sh.x = (short)f2bf(acc[nt][qq*4+0]);
      sh.y = (short)f2bf(acc[nt][qq*4+1]);
      sh.z = (short)f2bf(acc[nt][qq*4+2]);
      sh.w = (short)f2bf(acc[nt][qq*4+3]);
      int g2i = q * 16 + nt * 4 + qq;             // n-group
      *(short4*)(smem + g2i * 2048 + mL * 16 + hi * 8) = sh;
    }
  __syncthreads();                                // B6

  // ================= GEMM2 (swapped): C = W2 . h^T =================
  fx16 acc2;
#pragma unroll
  for (int r = 0; r < 16; r++) acc2[r] = 0.f;
  const int woff2 = (q * 32 + l31) * 512 + hi * 8;
  const char* hb = smem + mL * 16 + hi * 2048;
#pragma unroll
  for (int kt = 0; kt < 32; kt++) {
    bf16x8 bh = *(const bf16x8*)(hb + kt * 4096);
    bf16x8 wh = *(const bf16x8*)(const void*)(w2h + woff2 + kt * 16);
    bf16x8 wl = *(const bf16x8*)(const void*)(w2l + woff2 + kt * 16);
    acc2 = __builtin_amdgcn_mfma_f32_32x32x16_bf16(wh, bh, acc2, 0, 0, 0);
    acc2 = __builtin_amdgcn_mfma_f32_32x32x16_bf16(wl, bh, acc2, 0, 0, 0);
  }

  // ================= layer-2 epilogue =================
  {
    float p = 0.f;
#pragma unroll
    for (int r = 0; r < 16; r++) p += acc2[r] * acc2[r];
    p += __shfl_xor(p, 32);
    if (l < 32) red1[q * 128 + mL] = p;
  }
  __syncthreads();                                // B7
  float hn2s;
  {
    float s2 = red1[mL] + red1[128 + mL] + red1[256 + mL] + red1[384 + mL];
    float mxn = fmaxf(sqrtf(s2), MINN);
    float tv  = tanhf(mxn / xn2 * atanhf(fminf(xn2, ATEPS)));
    float sc  = tv / mxn;
    float hn  = fmaxf(tv, MINN);
    if (hn > MAXN) { sc *= MAXN / hn; hn = MAXN; }
    hn2s = hn;
#pragma unroll
    for (int r = 0; r < 16; r++) acc2[r] *= sc;
    float p = 0.f;
#pragma unroll
    for (int qq = 0; qq < 4; qq++) {
      float4 bv = *(const float4*)(b2s + q * 32 + qq * 8 + hi * 4);
      p += acc2[qq*4+0]*bv.x + acc2[qq*4+1]*bv.y + acc2[qq*4+2]*bv.z + acc2[qq*4+3]*bv.w;
    }
    p += __shfl_xor(p, 32);
    if (l < 32) red2[q * 128 + mL] = p;
  }
  __syncthreads();                                // B8
  {
    float xy = red2[mL] + red2[128 + mL] + red2[256 + mL] + red2[384 + mL];
    float y2 = sy[1];
    float x2 = hn2s * hn2s;
    float A  = 1.f + 2.f * xy + y2;
    float Bc = 1.f - x2;
    float den = fmaxf(1.f + 2.f * xy + x2 * y2, MINN);
    float Ai = A / den, Bi = Bc / den;
    float p = 0.f;
#pragma unroll
    for (int qq = 0; qq < 4; qq++) {
      float4 bv = *(const float4*)(b2s + q * 32 + qq * 8 + hi * 4);
      float g0 = Ai * acc2[qq*4+0] + Bi * bv.x;
      float g1 = Ai * acc2[qq*4+1] + Bi * bv.y;
      float g2 = Ai * acc2[qq*4+2] + Bi * bv.z;
      float g3 = Ai * acc2[qq*4+3] + Bi * bv.w;
      acc2[qq*4+0] = g0; acc2[qq*4+1] = g1; acc2[qq*4+2] = g2; acc2[qq*4+3] = g3;
      p += g0*g0 + g1*g1 + g2*g2 + g3*g3;
    }
    p += __shfl_xor(p, 32);
    if (l < 32) red3[q * 128 + mL] = p;
  }
  __syncthreads();                                // B9
  {
    float g2 = red3[mL] + red3[128 + mL] + red3[256 + mL] + red3[384 + mL];
    float gn = fmaxf(sqrtf(g2), MINN);
    float pf = (gn > MAXN) ? (MAXN / gn) : 1.f;
#pragma unroll
    for (int qq = 0; qq < 4; qq++) {
      float4 o;
      o.x = acc2[qq*4+0] * pf; o.y = acc2[qq*4+1] * pf;
      o.z = acc2[qq*4+2] * pf; o.w = acc2[qq*4+3] * pf;
      int byt = (mL * 512 + (q * 32 + qq * 8 + hi * 4) * 4) ^ ((mL & 7) << 4);
      *(float4*)(smem + byt) = o;                 // out f32 [128][128], swizzled
    }
  }
  __syncthreads();                                // B10
  {
    const int m0 = t >> 3, c = (t & 7) * 16;
    float* og = out + (rowBase + m0) * 128 + c;
#pragma unroll
    for (int ch = 0; ch < 4; ch++) {
      float4 v = *(const float4*)(smem + ((m0 * 512 + (c + ch * 4) * 4) ^ ((m0 & 7) << 4)));
      *(float4*)(og + ch * 4) = v;
    }
  }
}

extern "C" void kernel_launch(void* const* d_in, const int* in_sizes, int n_in,
                              void* d_out, int out_size, void* d_ws, size_t ws_size,
                              hipStream_t stream) {
  const float* x  = (const float*)d_in[0];  // [B,256]
  const float* W1 = (const float*)d_in[1];  // [512,256]
  const float* b1 = (const float*)d_in[2];  // [512]
  const float* W2 = (const float*)d_in[3];  // [128,512]
  const float* b2 = (const float*)d_in[4];  // [128]
  float* o = (float*)d_out;

  const int B = in_sizes[0] / 256;

  u16* w1h = (u16*)d_ws;              // [512*256]
  u16* w1l = w1h + 512 * 256;
  u16* w2h = w1l + 512 * 256;         // [128*512]
  u16* w2l = w2h + 128 * 512;         // total 786432 B

  cvtW<<<384, 512, 0, stream>>>(W1, W2, w1h, w1l, w2h, w2l);
  hyper<<<B / 128, 1024, 0, stream>>>(x, b1, b2, w1h, w1l, w2h, w2l, o);
}

// Round 4
// 272.128 us; speedup vs baseline: 1.2349x; 1.2349x over previous
//
#include <hip/hip_runtime.h>
#include <hip/hip_bf16.h>
#include <math.h>

#define MAXN 0.996f          /* (1 - 4e-3) / sqrt(c) */
#define MINN 1e-15f
#define ATEPS (1.0f - 1e-7f)

typedef unsigned short u16;
typedef __attribute__((ext_vector_type(8))) short bf16x8;
typedef __attribute__((ext_vector_type(16))) float fx16;

__device__ __forceinline__ u16 f2bf(float v) {
  union { __hip_bfloat16 b; u16 u; } cv; cv.b = __float2bfloat16(v); return cv.u;
}
__device__ __forceinline__ float bf2f(u16 u) {
  union { u16 u; __hip_bfloat16 b; } cv; cv.u = u; return __bfloat162float(cv.b);
}

// fast tanh / atanh: err ~1e-6, well under the 2e-3-scale tolerance.
__device__ __forceinline__ float ftanh(float x) {
  float ax = fabsf(x);
  float e = __expf(ax + ax);              // e^{2|x|}; inf for big -> r = 1
  float r = 1.f - 2.f / (e + 1.f);
  return copysignf(r, x);
}
__device__ __forceinline__ float fatanh(float z) {   // z in [0, 1-1e-7]
  return 0.5f * __logf((1.f + z) / (1.f - z));
}

// ---- split W into hi/lo bf16 planes ----
__global__ void cvtW(const float* __restrict__ W1, const float* __restrict__ W2,
                     u16* __restrict__ w1h, u16* __restrict__ w1l,
                     u16* __restrict__ w2h, u16* __restrict__ w2l) {
  int idx = blockIdx.x * 512 + threadIdx.x;
  if (idx < 512 * 256) {
    float v = W1[idx];
    u16 h = f2bf(v);
    w1h[idx] = h; w1l[idx] = f2bf(v - bf2f(h));
  } else {
    int j = idx - 512 * 256;   // < 128*512
    float v = W2[j];
    u16 h = f2bf(v);
    w2h[j] = h; w2l[j] = f2bf(v - bf2f(h));
  }
}

// k-blocked LDS layout for x/h (64 m-rows): group g = k>>3,
// byte = g*1024 + ((m*16) ^ ((g&7)<<4)) + (k&7)*2.
// GEMM reads (lanes = m, 16B) conflict-free; phase-0 writes ~4-way.

#define XHI   0            /* x hi [32 KB]  -> h groups 0..31 */
#define XLO   32768        /* x lo [32 KB]  -> h groups 32..63 (h overlays both) */
#define OSTG  65536        /* out stage f32 [64][128] swizzled, 32 KB */
#define B1S   98304
#define B2S   100352
#define XNL   100864
#define XN2L  101120
#define RED1  101376
#define RED2  103424
#define RED3  105472
#define RED4  107520
#define BNO   109568
#define SYO   109632

__global__ __launch_bounds__(512, 2) void hyper(
    const float* __restrict__ X,    // [B,256]
    const float* __restrict__ b1,   // [512]
    const float* __restrict__ b2,   // [128]
    const u16* __restrict__ w1h, const u16* __restrict__ w1l,   // [512,256]
    const u16* __restrict__ w2h, const u16* __restrict__ w2l,   // [128,512]
    float* __restrict__ out)        // [B,128]
{
  __shared__ __align__(16) char smem[109696];
  float* b1s  = (float*)(smem + B1S);
  float* b2s  = (float*)(smem + B2S);
  float* xnl  = (float*)(smem + XNL);
  float* xn2l = (float*)(smem + XN2L);
  float* red1 = (float*)(smem + RED1);
  float* red2 = (float*)(smem + RED2);
  float* red3 = (float*)(smem + RED3);
  float* red4 = (float*)(smem + RED4);
  float* bno  = (float*)(smem + BNO);
  float* sy   = (float*)(smem + SYO);

  const int t = threadIdx.x;
  const int w = t >> 6, l = t & 63, l31 = l & 31, hi = l >> 5;
  const long rowBase = (long)blockIdx.x * 64;

  // ================= phase 0: x -> LDS hi/lo (k-blocked), xn; b1/b2 =================
  {
    const int m0 = t >> 3, sub = t & 7;
    const float* xg = X + (rowBase + m0) * 256;
    float ss = 0.f;
#pragma unroll
    for (int j = 0; j < 8; j++) {
      float4 v = *(const float4*)(xg + (sub + j * 8) * 4);
      ss += v.x*v.x + v.y*v.y + v.z*v.z + v.w*v.w;
      u16 h0 = f2bf(v.x), h1 = f2bf(v.y), h2 = f2bf(v.z), h3 = f2bf(v.w);
      short4 sh; sh.x = (short)h0; sh.y = (short)h1; sh.z = (short)h2; sh.w = (short)h3;
      short4 sl;
      sl.x = (short)f2bf(v.x - bf2f(h0)); sl.y = (short)f2bf(v.y - bf2f(h1));
      sl.z = (short)f2bf(v.z - bf2f(h2)); sl.w = (short)f2bf(v.w - bf2f(h3));
      int c4 = sub + j * 8;                       // float4-quad index (k = c4*4)
      int g = c4 >> 1, p = c4 & 1;
      int byt = g * 1024 + ((m0 * 16) ^ ((g & 7) << 4)) + p * 8;
      *(short4*)(smem + byt) = sh;
      *(short4*)(smem + XLO + byt) = sl;
    }
    ss += __shfl_xor(ss, 1); ss += __shfl_xor(ss, 2); ss += __shfl_xor(ss, 4);
    if (sub == 0) xnl[m0] = sqrtf(ss);

    float bv = b1[t];
    b1s[t] = bv;
    float s1 = bv * bv;
    s1 += __shfl_xor(s1, 1); s1 += __shfl_xor(s1, 2); s1 += __shfl_xor(s1, 4);
    s1 += __shfl_xor(s1, 8); s1 += __shfl_xor(s1, 16); s1 += __shfl_xor(s1, 32);
    if (l == 0) bno[w] = s1;
    float cv2 = 0.f;
    if (t < 128) { cv2 = b2[t]; b2s[t] = cv2; }
    float s2 = cv2 * cv2;
    s2 += __shfl_xor(s2, 1); s2 += __shfl_xor(s2, 2); s2 += __shfl_xor(s2, 4);
    s2 += __shfl_xor(s2, 8); s2 += __shfl_xor(s2, 16); s2 += __shfl_xor(s2, 32);
    if (t < 128 && l == 0) bno[8 + w] = s2;
  }
  __syncthreads();                                // B1
  if (t == 0) {
    float a = 0.f;
#pragma unroll
    for (int j = 0; j < 8; j++) a += bno[j];
    sy[0] = a;
  }
  if (t == 64) sy[1] = bno[8] + bno[9];

  // ================= GEMM1 (swapped): C = W1 . x^T ; wave w owns n in [w*64, w*64+64) =====
  fx16 acc[2][2];                                 // [nt][mt]
#pragma unroll
  for (int a = 0; a < 2; a++)
#pragma unroll
    for (int b = 0; b < 2; b++)
#pragma unroll
      for (int r = 0; r < 16; r++) acc[a][b][r] = 0.f;

  const u16* w1hp0 = w1h + (w * 64 + l31) * 256 + hi * 8;
  const u16* w1lp0 = w1l + (w * 64 + l31) * 256 + hi * 8;
  const int xslot = l31 * 16;                     // + mt*512

#pragma unroll
  for (int kt = 0; kt < 16; kt++) {
    int g = kt * 2 + hi;
    int xb = g * 1024 + (xslot ^ ((g & 7) << 4));
    bf16x8 bh0 = *(const bf16x8*)(smem + xb);
    bf16x8 bh1 = *(const bf16x8*)(smem + xb + 512);
    bf16x8 bl0 = *(const bf16x8*)(smem + XLO + xb);
    bf16x8 bl1 = *(const bf16x8*)(smem + XLO + xb + 512);
#pragma unroll
    for (int nt = 0; nt < 2; nt++) {
      bf16x8 wh = *(const bf16x8*)(const void*)(w1hp0 + nt * 32 * 256 + kt * 16);
      bf16x8 wl = *(const bf16x8*)(const void*)(w1lp0 + nt * 32 * 256 + kt * 16);
      acc[nt][0] = __builtin_amdgcn_mfma_f32_32x32x16_bf16(wh, bh0, acc[nt][0], 0, 0, 0);
      acc[nt][1] = __builtin_amdgcn_mfma_f32_32x32x16_bf16(wh, bh1, acc[nt][1], 0, 0, 0);
      acc[nt][0] = __builtin_amdgcn_mfma_f32_32x32x16_bf16(wh, bl0, acc[nt][0], 0, 0, 0);
      acc[nt][1] = __builtin_amdgcn_mfma_f32_32x32x16_bf16(wh, bl1, acc[nt][1], 0, 0, 0);
      acc[nt][0] = __builtin_amdgcn_mfma_f32_32x32x16_bf16(wl, bh0, acc[nt][0], 0, 0, 0);
      acc[nt][1] = __builtin_amdgcn_mfma_f32_32x32x16_bf16(wl, bh1, acc[nt][1], 0, 0, 0);
    }
  }

  // ================= layer-1 epilogue (lane-local m = mt*32+l31) =================
  float hn[2], xn2v[2];
  {
#pragma unroll
    for (int mt = 0; mt < 2; mt++) {
      float p = 0.f;
#pragma unroll
      for (int nt = 0; nt < 2; nt++)
#pragma unroll
        for (int r = 0; r < 16; r++) p += acc[nt][mt][r] * acc[nt][mt][r];
      p += __shfl_xor(p, 32);
      if (l < 32) red1[w * 64 + mt * 32 + l31] = p;
    }
  }
  __syncthreads();                                // B2
  float4 bf[2][4];                                // b1 fragments (broadcast reads)
#pragma unroll
  for (int nt = 0; nt < 2; nt++)
#pragma unroll
    for (int qq = 0; qq < 4; qq++)
      bf[nt][qq] = *(const float4*)(b1s + w * 64 + nt * 32 + qq * 8 + hi * 4);
  {
#pragma unroll
    for (int mt = 0; mt < 2; mt++) {
      int m = mt * 32 + l31;
      float s2 = 0.f;
#pragma unroll
      for (int j = 0; j < 8; j++) s2 += red1[j * 64 + m];
      float xnv = fmaxf(xnl[m], MINN);
      float mxn = fmaxf(sqrtf(s2), MINN);
      float tv  = ftanh(mxn / xnv * fatanh(fminf(xnv, ATEPS)));
      float sc  = tv / mxn;
      float h   = fmaxf(tv, MINN);
      if (h > MAXN) { sc *= MAXN / h; h = MAXN; }
      hn[mt] = h;
      float p = 0.f;
#pragma unroll
      for (int nt = 0; nt < 2; nt++)
#pragma unroll
        for (int qq = 0; qq < 4; qq++) {
          float a0 = acc[nt][mt][qq*4+0] * sc, a1 = acc[nt][mt][qq*4+1] * sc;
          float a2 = acc[nt][mt][qq*4+2] * sc, a3 = acc[nt][mt][qq*4+3] * sc;
          acc[nt][mt][qq*4+0] = a0; acc[nt][mt][qq*4+1] = a1;
          acc[nt][mt][qq*4+2] = a2; acc[nt][mt][qq*4+3] = a3;
          p += a0*bf[nt][qq].x + a1*bf[nt][qq].y + a2*bf[nt][qq].z + a3*bf[nt][qq].w;
        }
      p += __shfl_xor(p, 32);
      if (l < 32) red2[w * 64 + m] = p;
    }
  }
  __syncthreads();                                // B3
  {
#pragma unroll
    for (int mt = 0; mt < 2; mt++) {
      int m = mt * 32 + l31;
      float xy = 0.f;
#pragma unroll
      for (int j = 0; j < 8; j++) xy += red2[j * 64 + m];
      float y2 = sy[0];
      float x2 = hn[mt] * hn[mt];
      float A  = 1.f + 2.f * xy + y2;
      float Bc = 1.f - x2;
      float den = fmaxf(1.f + 2.f * xy + x2 * y2, MINN);
      float Ai = A / den, Bi = Bc / den;
      float p = 0.f;
#pragma unroll
      for (int nt = 0; nt < 2; nt++)
#pragma unroll
        for (int qq = 0; qq < 4; qq++) {
          float g0 = Ai * acc[nt][mt][qq*4+0] + Bi * bf[nt][qq].x;
          float g1 = Ai * acc[nt][mt][qq*4+1] + Bi * bf[nt][qq].y;
          float g2 = Ai * acc[nt][mt][qq*4+2] + Bi * bf[nt][qq].z;
          float g3 = Ai * acc[nt][mt][qq*4+3] + Bi * bf[nt][qq].w;
          acc[nt][mt][qq*4+0] = g0; acc[nt][mt][qq*4+1] = g1;
          acc[nt][mt][qq*4+2] = g2; acc[nt][mt][qq*4+3] = g3;
          p += g0*g0 + g1*g1 + g2*g2 + g3*g3;
        }
      p += __shfl_xor(p, 32);
      if (l < 32) red3[w * 64 + m] = p;
    }
  }
  __syncthreads();                                // B4
  {
#pragma unroll
    for (int mt = 0; mt < 2; mt++) {
      int m = mt * 32 + l31;
      float g2 = 0.f;
#pragma unroll
      for (int j = 0; j < 8; j++) g2 += red3[j * 64 + m];
      float gn = fmaxf(sqrtf(g2), MINN);
      float pf = (gn > MAXN) ? (MAXN / gn) : 1.f;
      float gnp = fminf(gn, MAXN);
      float csc = pf * fatanh(fminf(gnp, ATEPS)) / gnp;
      float p = 0.f;
#pragma unroll
      for (int nt = 0; nt < 2; nt++)
#pragma unroll
        for (int r = 0; r < 16; r++) {
          float tvv = ftanh(csc * acc[nt][mt][r]);
          acc[nt][mt][r] = tvv;
          p += tvv * tvv;
        }
      p += __shfl_xor(p, 32);
      if (l < 32) red4[w * 64 + m] = p;
    }
  }
  __syncthreads();                                // B5
  {
#pragma unroll
    for (int mt = 0; mt < 2; mt++) {
      int m = mt * 32 + l31;
      float t2 = 0.f;
#pragma unroll
      for (int j = 0; j < 8; j++) t2 += red4[j * 64 + m];
      float tn = fmaxf(sqrtf(t2), MINN);
      float tv2 = ftanh(tn);
      float sc4 = tv2 / tn;
      float on = tv2;
      if (on > MAXN) { sc4 *= MAXN / on; on = MAXN; }
      xn2v[mt] = fmaxf(on, MINN);
      if (w == 0 && l < 32) xn2l[m] = xn2v[mt];
      // h -> LDS bf16 k-blocked (k dim = 512 features, groups 0..63)
#pragma unroll
      for (int nt = 0; nt < 2; nt++)
#pragma unroll
        for (int qq = 0; qq < 4; qq++) {
          short4 sh;
          sh.x = (short)f2bf(acc[nt][mt][qq*4+0] * sc4);
          sh.y = (short)f2bf(acc[nt][mt][qq*4+1] * sc4);
          sh.z = (short)f2bf(acc[nt][mt][qq*4+2] * sc4);
          sh.w = (short)f2bf(acc[nt][mt][qq*4+3] * sc4);
          int g2i = w * 8 + nt * 4 + qq;          // n-group (n = g2i*8 + hi*4 + 0..3)
          int byt = g2i * 1024 + ((m * 16) ^ ((g2i & 7) << 4)) + hi * 8;
          *(short4*)(smem + byt) = sh;
        }
    }
  }
  __syncthreads();                                // B6

  // ================= GEMM2 (swapped): C = W2 . h^T ; wave = (tile = w&3, mh = w>>2) =====
  const int tile = w & 3, mh = w >> 2;
  fx16 acc2;
#pragma unroll
  for (int r = 0; r < 16; r++) acc2[r] = 0.f;
  const u16* w2hp = w2h + (tile * 32 + l31) * 512 + hi * 8;
  const u16* w2lp = w2l + (tile * 32 + l31) * 512 + hi * 8;
  const int hslot = mh * 512 + l31 * 16;
#pragma unroll
  for (int kt = 0; kt < 32; kt++) {
    int g = kt * 2 + hi;
    int hb = g * 1024 + (hslot ^ ((g & 7) << 4));
    bf16x8 bh = *(const bf16x8*)(smem + hb);
    bf16x8 wh = *(const bf16x8*)(const void*)(w2hp + kt * 16);
    bf16x8 wl = *(const bf16x8*)(const void*)(w2lp + kt * 16);
    acc2 = __builtin_amdgcn_mfma_f32_32x32x16_bf16(wh, bh, acc2, 0, 0, 0);
    acc2 = __builtin_amdgcn_mfma_f32_32x32x16_bf16(wl, bh, acc2, 0, 0, 0);
  }

  // ================= layer-2 epilogue (lane-local m = mh*32 + l31) =================
  const int m2 = mh * 32 + l31;
  {
    float p = 0.f;
#pragma unroll
    for (int r = 0; r < 16; r++) p += acc2[r] * acc2[r];
    p += __shfl_xor(p, 32);
    if (l < 32) red1[tile * 64 + m2] = p;
  }
  __syncthreads();                                // B7
  float4 bf2[4];
#pragma unroll
  for (int qq = 0; qq < 4; qq++)
    bf2[qq] = *(const float4*)(b2s + tile * 32 + qq * 8 + hi * 4);
  float hn2;
  {
    float s2 = red1[m2] + red1[64 + m2] + red1[128 + m2] + red1[192 + m2];
    float xnv = xn2l[m2];
    float mxn = fmaxf(sqrtf(s2), MINN);
    float tv  = ftanh(mxn / xnv * fatanh(fminf(xnv, ATEPS)));
    float sc  = tv / mxn;
    float h   = fmaxf(tv, MINN);
    if (h > MAXN) { sc *= MAXN / h; h = MAXN; }
    hn2 = h;
    float p = 0.f;
#pragma unroll
    for (int qq = 0; qq < 4; qq++) {
      float a0 = acc2[qq*4+0] * sc, a1 = acc2[qq*4+1] * sc;
      float a2 = acc2[qq*4+2] * sc, a3 = acc2[qq*4+3] * sc;
      acc2[qq*4+0] = a0; acc2[qq*4+1] = a1; acc2[qq*4+2] = a2; acc2[qq*4+3] = a3;
      p += a0*bf2[qq].x + a1*bf2[qq].y + a2*bf2[qq].z + a3*bf2[qq].w;
    }
    p += __shfl_xor(p, 32);
    if (l < 32) red2[tile * 64 + m2] = p;
  }
  __syncthreads();                                // B8
  {
    float xy = red2[m2] + red2[64 + m2] + red2[128 + m2] + red2[192 + m2];
    float y2 = sy[1];
    float x2 = hn2 * hn2;
    float A  = 1.f + 2.f * xy + y2;
    float Bc = 1.f - x2;
    float den = fmaxf(1.f + 2.f * xy + x2 * y2, MINN);
    float Ai = A / den, Bi = Bc / den;
    float p = 0.f;
#pragma unroll
    for (int qq = 0; qq < 4; qq++) {
      float g0 = Ai * acc2[qq*4+0] + Bi * bf2[qq].x;
      float g1 = Ai * acc2[qq*4+1] + Bi * bf2[qq].y;
      float g2 = Ai * acc2[qq*4+2] + Bi * bf2[qq].z;
      float g3 = Ai * acc2[qq*4+3] + Bi * bf2[qq].w;
      acc2[qq*4+0] = g0; acc2[qq*4+1] = g1; acc2[qq*4+2] = g2; acc2[qq*4+3] = g3;
      p += g0*g0 + g1*g1 + g2*g2 + g3*g3;
    }
    p += __shfl_xor(p, 32);
    if (l < 32) red3[tile * 64 + m2] = p;
  }
  __syncthreads();                                // B9
  {
    float g2 = red3[m2] + red3[64 + m2] + red3[128 + m2] + red3[192 + m2];
    float gn = fmaxf(sqrtf(g2), MINN);
    float pf = (gn > MAXN) ? (MAXN / gn) : 1.f;
#pragma unroll
    for (int r = 0; r < 16; r++) {
      int n = tile * 32 + (r & 3) + 8 * (r >> 2) + 4 * hi;
      int byt = OSTG + m2 * 512 + ((n * 4) ^ ((m2 & 7) << 4));
      *(float*)(smem + byt) = acc2[r] * pf;
    }
  }
  __syncthreads();                                // B10
  {
    const int m0 = t >> 3, c = (t & 7) * 16;
    float* og = out + (rowBase + m0) * 128 + c;
#pragma unroll
    for (int ch = 0; ch < 4; ch++) {
      float4 v = *(const float4*)(smem + OSTG + m0 * 512 + (((c + ch * 4) * 4) ^ ((m0 & 7) << 4)));
      *(float4*)(og + ch * 4) = v;
    }
  }
}

extern "C" void kernel_launch(void* const* d_in, const int* in_sizes, int n_in,
                              void* d_out, int out_size, void* d_ws, size_t ws_size,
                              hipStream_t stream) {
  const float* x  = (const float*)d_in[0];  // [B,256]
  const float* W1 = (const float*)d_in[1];  // [512,256]
  const float* b1 = (const float*)d_in[2];  // [512]
  const float* W2 = (const float*)d_in[3];  // [128,512]
  const float* b2 = (const float*)d_in[4];  // [128]
  float* o = (float*)d_out;

  const int B = in_sizes[0] / 256;

  u16* w1h = (u16*)d_ws;              // [512*256]
  u16* w1l = w1h + 512 * 256;
  u16* w2h = w1l + 512 * 256;         // [128*512]
  u16* w2l = w2h + 128 * 512;         // total 786432 B

  cvtW<<<384, 512, 0, stream>>>(W1, W2, w1h, w1l, w2h, w2l);
  hyper<<<B / 64, 512, 0, stream>>>(x, b1, b2, w1h, w1l, w2h, w2l, o);
}

// Round 5
// 193.766 us; speedup vs baseline: 1.7343x; 1.4044x over previous
//
#include <hip/hip_runtime.h>
#include <hip/hip_bf16.h>
#include <math.h>

#define MAXN 0.996f          /* (1 - 4e-3) / sqrt(c) */
#define MINN 1e-15f
#define ATEPS (1.0f - 1e-7f)

typedef unsigned short u16;
typedef __attribute__((ext_vector_type(8))) short bf16x8;
typedef __attribute__((ext_vector_type(16))) float fx16;

__device__ __forceinline__ u16 f2bf(float v) {
  union { __hip_bfloat16 b; u16 u; } cv; cv.b = __float2bfloat16(v); return cv.u;
}
__device__ __forceinline__ float bf2f(u16 u) {
  union { u16 u; __hip_bfloat16 b; } cv; cv.u = u; return __bfloat162float(cv.b);
}

// fast tanh / atanh: err ~1e-6, well under the bf16-GEMM-scale tolerance.
__device__ __forceinline__ float ftanh(float x) {
  float ax = fabsf(x);
  float e = __expf(ax + ax);
  float r = 1.f - 2.f / (e + 1.f);
  return copysignf(r, x);
}
__device__ __forceinline__ float fatanh(float z) {   // z in [0, 1-1e-7]
  return 0.5f * __logf((1.f + z) / (1.f - z));
}

// ---- split W into hi/lo bf16 planes, FRAGMENT-PACKED ----
// W1 chunk c (c<16384): lane=c&63, blk=c>>6, kt=blk&15, n32=blk>>4,
//   hi=lane>>5, l31=lane&31 -> elems W1[n32*32+l31][kt*16+hi*8 + 0..7]
// W2 chunk c2 (c2<8192): kt=blk&31, n32=blk>>5 -> W2[n32*32+l31][kt*16+hi*8+0..7]
__global__ void cvtW(const float* __restrict__ W1, const float* __restrict__ W2,
                     u16* __restrict__ w1h, u16* __restrict__ w1l,
                     u16* __restrict__ w2h, u16* __restrict__ w2l) {
  int c = blockIdx.x * 512 + threadIdx.x;          // 24576 chunks total
  const float* src;
  u16 *dh, *dl;
  if (c < 16384) {
    int lane = c & 63, blk = c >> 6;
    int kt = blk & 15, n32 = blk >> 4;
    int n = n32 * 32 + (lane & 31), k0 = kt * 16 + (lane >> 5) * 8;
    src = W1 + n * 256 + k0;
    dh = w1h + c * 8; dl = w1l + c * 8;
  } else {
    int c2 = c - 16384;
    int lane = c2 & 63, blk = c2 >> 6;
    int kt = blk & 31, n32 = blk >> 5;
    int n = n32 * 32 + (lane & 31), k0 = kt * 16 + (lane >> 5) * 8;
    src = W2 + n * 512 + k0;
    dh = w2h + c2 * 8; dl = w2l + c2 * 8;
  }
  union { u16 u[8]; bf16x8 v; } ph, pl;
#pragma unroll
  for (int e = 0; e < 8; e++) {
    float v = src[e];
    u16 h = f2bf(v);
    ph.u[e] = h; pl.u[e] = f2bf(v - bf2f(h));
  }
  *(bf16x8*)dh = ph.v;
  *(bf16x8*)dl = pl.v;
}

// k-blocked LDS layout for x/h (64 m-rows): group g = k>>3,
// byte = g*1024 + ((m*16) ^ ((g&7)<<4)) + (k&7)*2.

#define XLO   32768        /* x hi at 0, x lo at 32K; h overlays 0..64K; out stage overlays 0..32K */
#define B1S   65536
#define B2S   67584
#define XNL   68096
#define XN2L  68352
#define RED1  68608
#define RED2  70656
#define RED4  72704
#define BNO   74752
#define SYO   74816

__global__ __launch_bounds__(512, 4) void hyper(
    const float* __restrict__ X,    // [B,256]
    const float* __restrict__ b1,   // [512]
    const float* __restrict__ b2,   // [128]
    const u16* __restrict__ w1h, const u16* __restrict__ w1l,
    const u16* __restrict__ w2h, const u16* __restrict__ w2l,
    float* __restrict__ out)        // [B,128]
{
  __shared__ __align__(16) char smem[74824];
  float* b1s  = (float*)(smem + B1S);
  float* b2s  = (float*)(smem + B2S);
  float* xnl  = (float*)(smem + XNL);
  float* xn2l = (float*)(smem + XN2L);
  float* red1 = (float*)(smem + RED1);
  float* red2 = (float*)(smem + RED2);
  float* red4 = (float*)(smem + RED4);
  float* bno  = (float*)(smem + BNO);
  float* sy   = (float*)(smem + SYO);

  const int t = threadIdx.x;
  const int w = t >> 6, l = t & 63, l31 = l & 31, hi = l >> 5;
  const long rowBase = (long)blockIdx.x * 64;

  // ================= phase 0: x -> LDS hi/lo (k-blocked), xn; b1/b2 =================
  {
    const int m0 = t >> 3, sub = t & 7;
    const float* xg = X + (rowBase + m0) * 256;
    float ss = 0.f;
#pragma unroll
    for (int j = 0; j < 8; j++) {
      float4 v = *(const float4*)(xg + (sub + j * 8) * 4);
      ss += v.x*v.x + v.y*v.y + v.z*v.z + v.w*v.w;
      u16 h0 = f2bf(v.x), h1 = f2bf(v.y), h2 = f2bf(v.z), h3 = f2bf(v.w);
      short4 sh; sh.x = (short)h0; sh.y = (short)h1; sh.z = (short)h2; sh.w = (short)h3;
      short4 sl;
      sl.x = (short)f2bf(v.x - bf2f(h0)); sl.y = (short)f2bf(v.y - bf2f(h1));
      sl.z = (short)f2bf(v.z - bf2f(h2)); sl.w = (short)f2bf(v.w - bf2f(h3));
      int c4 = sub + j * 8;
      int g = c4 >> 1, p = c4 & 1;
      int byt = g * 1024 + ((m0 * 16) ^ ((g & 7) << 4)) + p * 8;
      *(short4*)(smem + byt) = sh;
      *(short4*)(smem + XLO + byt) = sl;
    }
    ss += __shfl_xor(ss, 1); ss += __shfl_xor(ss, 2); ss += __shfl_xor(ss, 4);
    if (sub == 0) xnl[m0] = sqrtf(ss);

    float bv = b1[t];
    b1s[t] = bv;
    float s1 = bv * bv;
    s1 += __shfl_xor(s1, 1); s1 += __shfl_xor(s1, 2); s1 += __shfl_xor(s1, 4);
    s1 += __shfl_xor(s1, 8); s1 += __shfl_xor(s1, 16); s1 += __shfl_xor(s1, 32);
    if (l == 0) bno[w] = s1;
    float cv2 = 0.f;
    if (t < 128) { cv2 = b2[t]; b2s[t] = cv2; }
    float s2 = cv2 * cv2;
    s2 += __shfl_xor(s2, 1); s2 += __shfl_xor(s2, 2); s2 += __shfl_xor(s2, 4);
    s2 += __shfl_xor(s2, 8); s2 += __shfl_xor(s2, 16); s2 += __shfl_xor(s2, 32);
    if (t < 128 && l == 0) bno[8 + w] = s2;
  }
  __syncthreads();                                // B1
  if (t == 0) {
    float a = 0.f;
#pragma unroll
    for (int j = 0; j < 8; j++) a += bno[j];
    sy[0] = a;
  }
  if (t == 64) sy[1] = bno[8] + bno[9];

  // ===== GEMM1 (swapped): C = W1 . x^T ; wave w owns n in [w*64, w*64+64) =====
  fx16 acc[2][2];                                 // [nt][mt]
#pragma unroll
  for (int a = 0; a < 2; a++)
#pragma unroll
    for (int b = 0; b < 2; b++)
#pragma unroll
      for (int r = 0; r < 16; r++) acc[a][b][r] = 0.f;

  const bf16x8* W1H = (const bf16x8*)w1h;
  const bf16x8* W1L = (const bf16x8*)w1l;
  const int w1b0 = ((w * 2 + 0) * 16) * 64 + hi * 32 + l31;
  const int w1b1 = ((w * 2 + 1) * 16) * 64 + hi * 32 + l31;
  const int xslot = l31 * 16;

#pragma unroll
  for (int kt = 0; kt < 16; kt++) {
    int g = kt * 2 + hi;
    int xb = g * 1024 + (xslot ^ ((g & 7) << 4));
    bf16x8 bh0 = *(const bf16x8*)(smem + xb);
    bf16x8 bh1 = *(const bf16x8*)(smem + xb + 512);
    bf16x8 bl0 = *(const bf16x8*)(smem + XLO + xb);
    bf16x8 bl1 = *(const bf16x8*)(smem + XLO + xb + 512);
    bf16x8 wh0 = W1H[w1b0 + kt * 64];
    bf16x8 wl0 = W1L[w1b0 + kt * 64];
    bf16x8 wh1 = W1H[w1b1 + kt * 64];
    bf16x8 wl1 = W1L[w1b1 + kt * 64];
    acc[0][0] = __builtin_amdgcn_mfma_f32_32x32x16_bf16(wh0, bh0, acc[0][0], 0, 0, 0);
    acc[0][1] = __builtin_amdgcn_mfma_f32_32x32x16_bf16(wh0, bh1, acc[0][1], 0, 0, 0);
    acc[0][0] = __builtin_amdgcn_mfma_f32_32x32x16_bf16(wh0, bl0, acc[0][0], 0, 0, 0);
    acc[0][1] = __builtin_amdgcn_mfma_f32_32x32x16_bf16(wh0, bl1, acc[0][1], 0, 0, 0);
    acc[0][0] = __builtin_amdgcn_mfma_f32_32x32x16_bf16(wl0, bh0, acc[0][0], 0, 0, 0);
    acc[0][1] = __builtin_amdgcn_mfma_f32_32x32x16_bf16(wl0, bh1, acc[0][1], 0, 0, 0);
    acc[1][0] = __builtin_amdgcn_mfma_f32_32x32x16_bf16(wh1, bh0, acc[1][0], 0, 0, 0);
    acc[1][1] = __builtin_amdgcn_mfma_f32_32x32x16_bf16(wh1, bh1, acc[1][1], 0, 0, 0);
    acc[1][0] = __builtin_amdgcn_mfma_f32_32x32x16_bf16(wh1, bl0, acc[1][0], 0, 0, 0);
    acc[1][1] = __builtin_amdgcn_mfma_f32_32x32x16_bf16(wh1, bl1, acc[1][1], 0, 0, 0);
    acc[1][0] = __builtin_amdgcn_mfma_f32_32x32x16_bf16(wl1, bh0, acc[1][0], 0, 0, 0);
    acc[1][1] = __builtin_amdgcn_mfma_f32_32x32x16_bf16(wl1, bh1, acc[1][1], 0, 0, 0);
  }

  // ===== layer-1 epilogue, round 1: ||mx||^2 and <mx,b1> together =====
  float4 bf[2][4];
#pragma unroll
  for (int nt = 0; nt < 2; nt++)
#pragma unroll
    for (int qq = 0; qq < 4; qq++)
      bf[nt][qq] = *(const float4*)(b1s + w * 64 + nt * 32 + qq * 8 + hi * 4);
#pragma unroll
  for (int mt = 0; mt < 2; mt++) {
    float p1 = 0.f, p2 = 0.f;
#pragma unroll
    for (int nt = 0; nt < 2; nt++)
#pragma unroll
      for (int qq = 0; qq < 4; qq++) {
        float a0 = acc[nt][mt][qq*4+0], a1 = acc[nt][mt][qq*4+1];
        float a2 = acc[nt][mt][qq*4+2], a3 = acc[nt][mt][qq*4+3];
        p1 += a0*a0 + a1*a1 + a2*a2 + a3*a3;
        p2 += a0*bf[nt][qq].x + a1*bf[nt][qq].y + a2*bf[nt][qq].z + a3*bf[nt][qq].w;
      }
    p1 += __shfl_xor(p1, 32);
    p2 += __shfl_xor(p2, 32);
    if (l < 32) { red1[w * 64 + mt * 32 + l31] = p1; red2[w * 64 + mt * 32 + l31] = p2; }
  }
  __syncthreads();                                // B2

  // ===== layer-1: all scalars from reduced sums; tanh pass; ||t||^2 =====
#pragma unroll
  for (int mt = 0; mt < 2; mt++) {
    int m = mt * 32 + l31;
    float s2 = 0.f, xyr = 0.f;
#pragma unroll
    for (int j = 0; j < 8; j++) { s2 += red1[j * 64 + m]; xyr += red2[j * 64 + m]; }
    float xnv = fmaxf(xnl[m], MINN);
    float mxn = fmaxf(sqrtf(s2), MINN);
    float tv  = ftanh(mxn / xnv * fatanh(fminf(xnv, ATEPS)));
    float sc  = tv / mxn;
    float hn  = fmaxf(tv, MINN);
    if (hn > MAXN) { sc *= MAXN / hn; hn = MAXN; }
    float xy = sc * xyr;
    float y2 = sy[0];
    float x2 = hn * hn;
    float A  = 1.f + 2.f * xy + y2;
    float Bc = 1.f - x2;
    float den = fmaxf(1.f + 2.f * xy + x2 * y2, MINN);
    float Ai = A / den, Bi = Bc / den;
    float g2s = Ai*Ai*x2 + 2.f*Ai*Bi*xy + Bi*Bi*y2;   // ||g||^2 from scalars
    float gn = fmaxf(sqrtf(g2s), MINN);
    float pf = (gn > MAXN) ? (MAXN / gn) : 1.f;
    float gnp = fminf(gn, MAXN);
    float csc = pf * fatanh(fminf(gnp, ATEPS)) / gnp;
    float Asc = Ai * sc;
    float p4 = 0.f;
#pragma unroll
    for (int nt = 0; nt < 2; nt++)
#pragma unroll
      for (int qq = 0; qq < 4; qq++) {
        float t0 = ftanh(csc * (Asc * acc[nt][mt][qq*4+0] + Bi * bf[nt][qq].x));
        float t1 = ftanh(csc * (Asc * acc[nt][mt][qq*4+1] + Bi * bf[nt][qq].y));
        float t2 = ftanh(csc * (Asc * acc[nt][mt][qq*4+2] + Bi * bf[nt][qq].z));
        float t3 = ftanh(csc * (Asc * acc[nt][mt][qq*4+3] + Bi * bf[nt][qq].w));
        acc[nt][mt][qq*4+0] = t0; acc[nt][mt][qq*4+1] = t1;
        acc[nt][mt][qq*4+2] = t2; acc[nt][mt][qq*4+3] = t3;
        p4 += t0*t0 + t1*t1 + t2*t2 + t3*t3;
      }
    p4 += __shfl_xor(p4, 32);
    if (l < 32) red4[w * 64 + m] = p4;
  }
  __syncthreads();                                // B3

  // ===== layer-1 final: expmap0 scale; h -> LDS bf16 =====
#pragma unroll
  for (int mt = 0; mt < 2; mt++) {
    int m = mt * 32 + l31;
    float t2 = 0.f;
#pragma unroll
    for (int j = 0; j < 8; j++) t2 += red4[j * 64 + m];
    float tn = fmaxf(sqrtf(t2), MINN);
    float tv2 = ftanh(tn);
    float sc4 = tv2 / tn;
    float on = tv2;
    if (on > MAXN) { sc4 *= MAXN / on; on = MAXN; }
    if (w == 0 && l < 32) xn2l[m] = fmaxf(on, MINN);
#pragma unroll
    for (int nt = 0; nt < 2; nt++)
#pragma unroll
      for (int qq = 0; qq < 4; qq++) {
        short4 sh;
        sh.x = (short)f2bf(acc[nt][mt][qq*4+0] * sc4);
        sh.y = (short)f2bf(acc[nt][mt][qq*4+1] * sc4);
        sh.z = (short)f2bf(acc[nt][mt][qq*4+2] * sc4);
        sh.w = (short)f2bf(acc[nt][mt][qq*4+3] * sc4);
        int g2i = w * 8 + nt * 4 + qq;
        int byt = g2i * 1024 + ((m * 16) ^ ((g2i & 7) << 4)) + hi * 8;
        *(short4*)(smem + byt) = sh;
      }
  }
  __syncthreads();                                // B4

  // ===== GEMM2 (swapped): C = W2 . h^T ; wave = (tile = w&3, mh = w>>2) =====
  const int tile = w & 3, mh = w >> 2;
  fx16 acc2;
#pragma unroll
  for (int r = 0; r < 16; r++) acc2[r] = 0.f;
  const bf16x8* W2H = (const bf16x8*)w2h;
  const bf16x8* W2L = (const bf16x8*)w2l;
  const int w2b = (tile * 32) * 64 + hi * 32 + l31;
  const int hslot = mh * 512 + l31 * 16;
#pragma unroll
  for (int kt = 0; kt < 32; kt++) {
    int g = kt * 2 + hi;
    int hb = g * 1024 + (hslot ^ ((g & 7) << 4));
    bf16x8 bh = *(const bf16x8*)(smem + hb);
    bf16x8 wh = W2H[w2b + kt * 64];
    bf16x8 wl = W2L[w2b + kt * 64];
    acc2 = __builtin_amdgcn_mfma_f32_32x32x16_bf16(wh, bh, acc2, 0, 0, 0);
    acc2 = __builtin_amdgcn_mfma_f32_32x32x16_bf16(wl, bh, acc2, 0, 0, 0);
  }

  // ===== layer-2 epilogue: one reduction round =====
  const int m2 = mh * 32 + l31;
  float4 bf2[4];
#pragma unroll
  for (int qq = 0; qq < 4; qq++)
    bf2[qq] = *(const float4*)(b2s + tile * 32 + qq * 8 + hi * 4);
  {
    float p1 = 0.f, p2 = 0.f;
#pragma unroll
    for (int qq = 0; qq < 4; qq++) {
      float a0 = acc2[qq*4+0], a1 = acc2[qq*4+1], a2 = acc2[qq*4+2], a3 = acc2[qq*4+3];
      p1 += a0*a0 + a1*a1 + a2*a2 + a3*a3;
      p2 += a0*bf2[qq].x + a1*bf2[qq].y + a2*bf2[qq].z + a3*bf2[qq].w;
    }
    p1 += __shfl_xor(p1, 32);
    p2 += __shfl_xor(p2, 32);
    if (l < 32) { red1[tile * 64 + m2] = p1; red2[tile * 64 + m2] = p2; }
  }
  __syncthreads();                                // B5
  {
    float s2 = red1[m2] + red1[64 + m2] + red1[128 + m2] + red1[192 + m2];
    float xyr = red2[m2] + red2[64 + m2] + red2[128 + m2] + red2[192 + m2];
    float xnv = xn2l[m2];
    float mxn = fmaxf(sqrtf(s2), MINN);
    float tv  = ftanh(mxn / xnv * fatanh(fminf(xnv, ATEPS)));
    float sc  = tv / mxn;
    float hn  = fmaxf(tv, MINN);
    if (hn > MAXN) { sc *= MAXN / hn; hn = MAXN; }
    float xy = sc * xyr;
    float y2 = sy[1];
    float x2 = hn * hn;
    float A  = 1.f + 2.f * xy + y2;
    float Bc = 1.f - x2;
    float den = fmaxf(1.f + 2.f * xy + x2 * y2, MINN);
    float Ai = A / den, Bi = Bc / den;
    float g2s = Ai*Ai*x2 + 2.f*Ai*Bi*xy + Bi*Bi*y2;
    float gn = fmaxf(sqrtf(g2s), MINN);
    float pf = (gn > MAXN) ? (MAXN / gn) : 1.f;
    float As = pf * Ai * sc, Bs = pf * Bi;
#pragma unroll
    for (int qq = 0; qq < 4; qq++) {
      float o0 = As * acc2[qq*4+0] + Bs * bf2[qq].x;
      float o1 = As * acc2[qq*4+1] + Bs * bf2[qq].y;
      float o2 = As * acc2[qq*4+2] + Bs * bf2[qq].z;
      float o3 = As * acc2[qq*4+3] + Bs * bf2[qq].w;
      int n0 = tile * 32 + qq * 8 + 4 * hi;       // r = qq*4+j -> n = tile*32 + j + 8*qq + 4*hi
      int base = m2 * 512;
      *(float*)(smem + base + (((n0 + 0) * 4) ^ ((m2 & 7) << 4))) = o0;
      *(float*)(smem + base + (((n0 + 1) * 4) ^ ((m2 & 7) << 4))) = o1;
      *(float*)(smem + base + (((n0 + 2) * 4) ^ ((m2 & 7) << 4))) = o2;
      *(float*)(smem + base + (((n0 + 3) * 4) ^ ((m2 & 7) << 4))) = o3;
    }
  }
  __syncthreads();                                // B6
  {
    const int m0 = t >> 3, c = (t & 7) * 16;
    float* og = out + (rowBase + m0) * 128 + c;
#pragma unroll
    for (int ch = 0; ch < 4; ch++) {
      float4 v = *(const float4*)(smem + m0 * 512 + (((c + ch * 4) * 4) ^ ((m0 & 7) << 4)));
      *(float4*)(og + ch * 4) = v;
    }
  }
}

extern "C" void kernel_launch(void* const* d_in, const int* in_sizes, int n_in,
                              void* d_out, int out_size, void* d_ws, size_t ws_size,
                              hipStream_t stream) {
  const float* x  = (const float*)d_in[0];  // [B,256]
  const float* W1 = (const float*)d_in[1];  // [512,256]
  const float* b1 = (const float*)d_in[2];  // [512]
  const float* W2 = (const float*)d_in[3];  // [128,512]
  const float* b2 = (const float*)d_in[4];  // [128]
  float* o = (float*)d_out;

  const int B = in_sizes[0] / 256;

  u16* w1h = (u16*)d_ws;              // packed [16384][8]
  u16* w1l = w1h + 512 * 256;
  u16* w2h = w1l + 512 * 256;         // packed [8192][8]
  u16* w2l = w2h + 128 * 512;         // total 786432 B

  cvtW<<<48, 512, 0, stream>>>(W1, W2, w1h, w1l, w2h, w2l);
  hyper<<<B / 64, 512, 0, stream>>>(x, b1, b2, w1h, w1l, w2h, w2l, o);
}

// Round 6
// 171.447 us; speedup vs baseline: 1.9601x; 1.1302x over previous
//
#include <hip/hip_runtime.h>
#include <hip/hip_bf16.h>
#include <math.h>

#define MAXN 0.996f          /* (1 - 4e-3) / sqrt(c) */
#define MINN 1e-15f
#define ATEPS (1.0f - 1e-7f)

typedef unsigned short u16;
typedef __attribute__((ext_vector_type(8))) short bf16x8;
typedef __attribute__((ext_vector_type(16))) float fx16;

__device__ __forceinline__ u16 f2bf(float v) {
  union { __hip_bfloat16 b; u16 u; } cv; cv.b = __float2bfloat16(v); return cv.u;
}
__device__ __forceinline__ float bf2f(u16 u) {
  union { u16 u; __hip_bfloat16 b; } cv; cv.u = u; return __bfloat162float(cv.b);
}

// fast tanh / atanh: err ~1e-6, well under the bf16-GEMM-scale tolerance.
__device__ __forceinline__ float ftanh(float x) {
  float ax = fabsf(x);
  float e = __expf(ax + ax);
  float r = 1.f - 2.f / (e + 1.f);
  return copysignf(r, x);
}
__device__ __forceinline__ float fatanh(float z) {   // z in [0, 1-1e-7]
  return 0.5f * __logf((1.f + z) / (1.f - z));
}

// ---- split W into hi/lo bf16 planes, FRAGMENT-PACKED ----
// W1 chunk c (c<16384): lane=c&63, blk=c>>6, kt=blk&15, n32=blk>>4,
//   hi=lane>>5, l31=lane&31 -> elems W1[n32*32+l31][kt*16+hi*8 + 0..7]
// W2 chunk c2 (c2<8192): kt=blk&31, n32=blk>>5 -> W2[n32*32+l31][kt*16+hi*8+0..7]
__global__ void cvtW(const float* __restrict__ W1, const float* __restrict__ W2,
                     u16* __restrict__ w1h, u16* __restrict__ w1l,
                     u16* __restrict__ w2h, u16* __restrict__ w2l) {
  int c = blockIdx.x * 256 + threadIdx.x;          // 24576 chunks total
  const float* src;
  u16 *dh, *dl;
  if (c < 16384) {
    int lane = c & 63, blk = c >> 6;
    int kt = blk & 15, n32 = blk >> 4;
    int n = n32 * 32 + (lane & 31), k0 = kt * 16 + (lane >> 5) * 8;
    src = W1 + n * 256 + k0;
    dh = w1h + c * 8; dl = w1l + c * 8;
  } else {
    int c2 = c - 16384;
    int lane = c2 & 63, blk = c2 >> 6;
    int kt = blk & 31, n32 = blk >> 5;
    int n = n32 * 32 + (lane & 31), k0 = kt * 16 + (lane >> 5) * 8;
    src = W2 + n * 512 + k0;
    dh = w2h + c2 * 8; dl = w2l + c2 * 8;
  }
  union { u16 u[8]; bf16x8 v; } ph, pl;
#pragma unroll
  for (int e = 0; e < 8; e++) {
    float v = src[e];
    u16 h = f2bf(v);
    ph.u[e] = h; pl.u[e] = f2bf(v - bf2f(h));
  }
  *(bf16x8*)dh = ph.v;
  *(bf16x8*)dl = pl.v;
}

// k-blocked LDS layout for x/h (64 m-rows): group g = k>>3,
// byte = g*1024 + ((m*16) ^ ((g&7)<<4)) + (k&7)*2.

#define B1S   65536        /* x hi in 0..32K; h overlays 0..64K; out stage overlays 0..32K */
#define B2S   67584
#define XNL   68096
#define XN2L  68352
#define RED1  68608
#define RED2  70656
#define RED4  72704
#define BNO   74752
#define SYO   74816

__global__ __launch_bounds__(512, 4) void hyper(
    const float* __restrict__ X,    // [B,256]
    const float* __restrict__ b1,   // [512]
    const float* __restrict__ b2,   // [128]
    const u16* __restrict__ w1h, const u16* __restrict__ w1l,
    const u16* __restrict__ w2h, const u16* __restrict__ w2l,
    float* __restrict__ out)        // [B,128]
{
  __shared__ __align__(16) char smem[74824];
  float* b1s  = (float*)(smem + B1S);
  float* b2s  = (float*)(smem + B2S);
  float* xnl  = (float*)(smem + XNL);
  float* xn2l = (float*)(smem + XN2L);
  float* red1 = (float*)(smem + RED1);
  float* red2 = (float*)(smem + RED2);
  float* red4 = (float*)(smem + RED4);
  float* bno  = (float*)(smem + BNO);
  float* sy   = (float*)(smem + SYO);

  const int t = threadIdx.x;
  const int w = t >> 6, l = t & 63, l31 = l & 31, hi = l >> 5;
  const long rowBase = (long)blockIdx.x * 64;

  // ================= phase 0: x -> LDS bf16-hi (k-blocked), xn; b1/b2 =================
  {
    const int m0 = t >> 3, sub = t & 7;
    const float* xg = X + (rowBase + m0) * 256;
    float ss = 0.f;
#pragma unroll
    for (int j = 0; j < 8; j++) {
      float4 v = *(const float4*)(xg + (sub + j * 8) * 4);
      ss += v.x*v.x + v.y*v.y + v.z*v.z + v.w*v.w;
      short4 sh;
      sh.x = (short)f2bf(v.x); sh.y = (short)f2bf(v.y);
      sh.z = (short)f2bf(v.z); sh.w = (short)f2bf(v.w);
      int c4 = sub + j * 8;
      int g = c4 >> 1, p = c4 & 1;
      int byt = g * 1024 + ((m0 * 16) ^ ((g & 7) << 4)) + p * 8;
      *(short4*)(smem + byt) = sh;
    }
    ss += __shfl_xor(ss, 1); ss += __shfl_xor(ss, 2); ss += __shfl_xor(ss, 4);
    if (sub == 0) xnl[m0] = sqrtf(ss);

    float bv = b1[t];
    b1s[t] = bv;
    float s1 = bv * bv;
    s1 += __shfl_xor(s1, 1); s1 += __shfl_xor(s1, 2); s1 += __shfl_xor(s1, 4);
    s1 += __shfl_xor(s1, 8); s1 += __shfl_xor(s1, 16); s1 += __shfl_xor(s1, 32);
    if (l == 0) bno[w] = s1;
    float cv2 = 0.f;
    if (t < 128) { cv2 = b2[t]; b2s[t] = cv2; }
    float s2 = cv2 * cv2;
    s2 += __shfl_xor(s2, 1); s2 += __shfl_xor(s2, 2); s2 += __shfl_xor(s2, 4);
    s2 += __shfl_xor(s2, 8); s2 += __shfl_xor(s2, 16); s2 += __shfl_xor(s2, 32);
    if (t < 128 && l == 0) bno[8 + w] = s2;
  }
  __syncthreads();                                // B1
  if (t == 0) {
    float a = 0.f;
#pragma unroll
    for (int j = 0; j < 8; j++) a += bno[j];
    sy[0] = a;
  }
  if (t == 64) sy[1] = bno[8] + bno[9];

  // ===== GEMM1 (swapped, 2-pass): C = W1 . x^T ; wave w owns n in [w*64, w*64+64) =====
  fx16 acc[2][2];                                 // [nt][mt]
#pragma unroll
  for (int a = 0; a < 2; a++)
#pragma unroll
    for (int b = 0; b < 2; b++)
#pragma unroll
      for (int r = 0; r < 16; r++) acc[a][b][r] = 0.f;

  const bf16x8* W1H = (const bf16x8*)w1h;
  const bf16x8* W1L = (const bf16x8*)w1l;
  const int w1b0 = ((w * 2 + 0) * 16) * 64 + hi * 32 + l31;
  const int w1b1 = ((w * 2 + 1) * 16) * 64 + hi * 32 + l31;
  const int xslot = l31 * 16;

#pragma unroll
  for (int kt = 0; kt < 16; kt++) {
    int g = kt * 2 + hi;
    int xb = g * 1024 + (xslot ^ ((g & 7) << 4));
    bf16x8 bh0 = *(const bf16x8*)(smem + xb);
    bf16x8 bh1 = *(const bf16x8*)(smem + xb + 512);
    bf16x8 wh0 = W1H[w1b0 + kt * 64];
    bf16x8 wl0 = W1L[w1b0 + kt * 64];
    bf16x8 wh1 = W1H[w1b1 + kt * 64];
    bf16x8 wl1 = W1L[w1b1 + kt * 64];
    acc[0][0] = __builtin_amdgcn_mfma_f32_32x32x16_bf16(wh0, bh0, acc[0][0], 0, 0, 0);
    acc[0][1] = __builtin_amdgcn_mfma_f32_32x32x16_bf16(wh0, bh1, acc[0][1], 0, 0, 0);
    acc[1][0] = __builtin_amdgcn_mfma_f32_32x32x16_bf16(wh1, bh0, acc[1][0], 0, 0, 0);
    acc[1][1] = __builtin_amdgcn_mfma_f32_32x32x16_bf16(wh1, bh1, acc[1][1], 0, 0, 0);
    acc[0][0] = __builtin_amdgcn_mfma_f32_32x32x16_bf16(wl0, bh0, acc[0][0], 0, 0, 0);
    acc[0][1] = __builtin_amdgcn_mfma_f32_32x32x16_bf16(wl0, bh1, acc[0][1], 0, 0, 0);
    acc[1][0] = __builtin_amdgcn_mfma_f32_32x32x16_bf16(wl1, bh0, acc[1][0], 0, 0, 0);
    acc[1][1] = __builtin_amdgcn_mfma_f32_32x32x16_bf16(wl1, bh1, acc[1][1], 0, 0, 0);
  }

  // ===== layer-1 epilogue, round 1: ||mx||^2 and <mx,b1> together =====
  // b1 fragments are re-read from LDS at each use (broadcast, ~free) so the
  // 32-reg bf cache never lives across a barrier -> no spill at the 128 cap.
#pragma unroll
  for (int mt = 0; mt < 2; mt++) {
    float p1 = 0.f, p2 = 0.f;
#pragma unroll
    for (int nt = 0; nt < 2; nt++)
#pragma unroll
      for (int qq = 0; qq < 4; qq++) {
        float4 bv = *(const float4*)(b1s + w * 64 + nt * 32 + qq * 8 + hi * 4);
        float a0 = acc[nt][mt][qq*4+0], a1 = acc[nt][mt][qq*4+1];
        float a2 = acc[nt][mt][qq*4+2], a3 = acc[nt][mt][qq*4+3];
        p1 += a0*a0 + a1*a1 + a2*a2 + a3*a3;
        p2 += a0*bv.x + a1*bv.y + a2*bv.z + a3*bv.w;
      }
    p1 += __shfl_xor(p1, 32);
    p2 += __shfl_xor(p2, 32);
    if (l < 32) { red1[w * 64 + mt * 32 + l31] = p1; red2[w * 64 + mt * 32 + l31] = p2; }
  }
  __syncthreads();                                // B2

  // ===== layer-1: all scalars from reduced sums; tanh pass; ||t||^2 =====
#pragma unroll
  for (int mt = 0; mt < 2; mt++) {
    int m = mt * 32 + l31;
    float s2 = 0.f, xyr = 0.f;
#pragma unroll
    for (int j = 0; j < 8; j++) { s2 += red1[j * 64 + m]; xyr += red2[j * 64 + m]; }
    float xnv = fmaxf(xnl[m], MINN);
    float mxn = fmaxf(sqrtf(s2), MINN);
    float tv  = ftanh(mxn / xnv * fatanh(fminf(xnv, ATEPS)));
    float sc  = tv / mxn;
    float hn  = fmaxf(tv, MINN);
    if (hn > MAXN) { sc *= MAXN / hn; hn = MAXN; }
    float xy = sc * xyr;
    float y2 = sy[0];
    float x2 = hn * hn;
    float A  = 1.f + 2.f * xy + y2;
    float Bc = 1.f - x2;
    float den = fmaxf(1.f + 2.f * xy + x2 * y2, MINN);
    float Ai = A / den, Bi = Bc / den;
    float g2s = Ai*Ai*x2 + 2.f*Ai*Bi*xy + Bi*Bi*y2;   // ||g||^2 from scalars
    float gn = fmaxf(sqrtf(g2s), MINN);
    float pf = (gn > MAXN) ? (MAXN / gn) : 1.f;
    float gnp = fminf(gn, MAXN);
    float csc = pf * fatanh(fminf(gnp, ATEPS)) / gnp;
    float Asc = Ai * sc;
    float p4 = 0.f;
#pragma unroll
    for (int nt = 0; nt < 2; nt++)
#pragma unroll
      for (int qq = 0; qq < 4; qq++) {
        float4 bv = *(const float4*)(b1s + w * 64 + nt * 32 + qq * 8 + hi * 4);
        float t0 = ftanh(csc * (Asc * acc[nt][mt][qq*4+0] + Bi * bv.x));
        float t1 = ftanh(csc * (Asc * acc[nt][mt][qq*4+1] + Bi * bv.y));
        float t2 = ftanh(csc * (Asc * acc[nt][mt][qq*4+2] + Bi * bv.z));
        float t3 = ftanh(csc * (Asc * acc[nt][mt][qq*4+3] + Bi * bv.w));
        acc[nt][mt][qq*4+0] = t0; acc[nt][mt][qq*4+1] = t1;
        acc[nt][mt][qq*4+2] = t2; acc[nt][mt][qq*4+3] = t3;
        p4 += t0*t0 + t1*t1 + t2*t2 + t3*t3;
      }
    p4 += __shfl_xor(p4, 32);
    if (l < 32) red4[w * 64 + m] = p4;
  }
  __syncthreads();                                // B3

  // ===== layer-1 final: expmap0 scale; h -> LDS bf16 =====
#pragma unroll
  for (int mt = 0; mt < 2; mt++) {
    int m = mt * 32 + l31;
    float t2 = 0.f;
#pragma unroll
    for (int j = 0; j < 8; j++) t2 += red4[j * 64 + m];
    float tn = fmaxf(sqrtf(t2), MINN);
    float tv2 = ftanh(tn);
    float sc4 = tv2 / tn;
    float on = tv2;
    if (on > MAXN) { sc4 *= MAXN / on; on = MAXN; }
    if (w == 0 && l < 32) xn2l[m] = fmaxf(on, MINN);
#pragma unroll
    for (int nt = 0; nt < 2; nt++)
#pragma unroll
      for (int qq = 0; qq < 4; qq++) {
        short4 sh;
        sh.x = (short)f2bf(acc[nt][mt][qq*4+0] * sc4);
        sh.y = (short)f2bf(acc[nt][mt][qq*4+1] * sc4);
        sh.z = (short)f2bf(acc[nt][mt][qq*4+2] * sc4);
        sh.w = (short)f2bf(acc[nt][mt][qq*4+3] * sc4);
        int g2i = w * 8 + nt * 4 + qq;
        int byt = g2i * 1024 + ((m * 16) ^ ((g2i & 7) << 4)) + hi * 8;
        *(short4*)(smem + byt) = sh;
      }
  }
  __syncthreads();                                // B4

  // ===== GEMM2 (swapped): C = W2 . h^T ; wave = (tile = w&3, mh = w>>2) =====
  const int tile = w & 3, mh = w >> 2;
  fx16 acc2;
#pragma unroll
  for (int r = 0; r < 16; r++) acc2[r] = 0.f;
  const bf16x8* W2H = (const bf16x8*)w2h;
  const bf16x8* W2L = (const bf16x8*)w2l;
  const int w2b = (tile * 32) * 64 + hi * 32 + l31;
  const int hslot = mh * 512 + l31 * 16;
#pragma unroll
  for (int kt = 0; kt < 32; kt++) {
    int g = kt * 2 + hi;
    int hb = g * 1024 + (hslot ^ ((g & 7) << 4));
    bf16x8 bh = *(const bf16x8*)(smem + hb);
    bf16x8 wh = W2H[w2b + kt * 64];
    bf16x8 wl = W2L[w2b + kt * 64];
    acc2 = __builtin_amdgcn_mfma_f32_32x32x16_bf16(wh, bh, acc2, 0, 0, 0);
    acc2 = __builtin_amdgcn_mfma_f32_32x32x16_bf16(wl, bh, acc2, 0, 0, 0);
  }

  // ===== layer-2 epilogue: one reduction round =====
  const int m2 = mh * 32 + l31;
  {
    float p1 = 0.f, p2 = 0.f;
#pragma unroll
    for (int qq = 0; qq < 4; qq++) {
      float4 bv = *(const float4*)(b2s + tile * 32 + qq * 8 + hi * 4);
      float a0 = acc2[qq*4+0], a1 = acc2[qq*4+1], a2 = acc2[qq*4+2], a3 = acc2[qq*4+3];
      p1 += a0*a0 + a1*a1 + a2*a2 + a3*a3;
      p2 += a0*bv.x + a1*bv.y + a2*bv.z + a3*bv.w;
    }
    p1 += __shfl_xor(p1, 32);
    p2 += __shfl_xor(p2, 32);
    if (l < 32) { red1[tile * 64 + m2] = p1; red2[tile * 64 + m2] = p2; }
  }
  __syncthreads();                                // B5
  {
    float s2 = red1[m2] + red1[64 + m2] + red1[128 + m2] + red1[192 + m2];
    float xyr = red2[m2] + red2[64 + m2] + red2[128 + m2] + red2[192 + m2];
    float xnv = xn2l[m2];
    float mxn = fmaxf(sqrtf(s2), MINN);
    float tv  = ftanh(mxn / xnv * fatanh(fminf(xnv, ATEPS)));
    float sc  = tv / mxn;
    float hn  = fmaxf(tv, MINN);
    if (hn > MAXN) { sc *= MAXN / hn; hn = MAXN; }
    float xy = sc * xyr;
    float y2 = sy[1];
    float x2 = hn * hn;
    float A  = 1.f + 2.f * xy + y2;
    float Bc = 1.f - x2;
    float den = fmaxf(1.f + 2.f * xy + x2 * y2, MINN);
    float Ai = A / den, Bi = Bc / den;
    float g2s = Ai*Ai*x2 + 2.f*Ai*Bi*xy + Bi*Bi*y2;
    float gn = fmaxf(sqrtf(g2s), MINN);
    float pf = (gn > MAXN) ? (MAXN / gn) : 1.f;
    float As = pf * Ai * sc, Bs = pf * Bi;
#pragma unroll
    for (int qq = 0; qq < 4; qq++) {
      float4 bv = *(const float4*)(b2s + tile * 32 + qq * 8 + hi * 4);
      float o0 = As * acc2[qq*4+0] + Bs * bv.x;
      float o1 = As * acc2[qq*4+1] + Bs * bv.y;
      float o2 = As * acc2[qq*4+2] + Bs * bv.z;
      float o3 = As * acc2[qq*4+3] + Bs * bv.w;
      int n0 = tile * 32 + qq * 8 + 4 * hi;
      int base = m2 * 512;
      *(float*)(smem + base + (((n0 + 0) * 4) ^ ((m2 & 7) << 4))) = o0;
      *(float*)(smem + base + (((n0 + 1) * 4) ^ ((m2 & 7) << 4))) = o1;
      *(float*)(smem + base + (((n0 + 2) * 4) ^ ((m2 & 7) << 4))) = o2;
      *(float*)(smem + base + (((n0 + 3) * 4) ^ ((m2 & 7) << 4))) = o3;
    }
  }
  __syncthreads();                                // B6
  {
    const int m0 = t >> 3, c = (t & 7) * 16;
    float* og = out + (rowBase + m0) * 128 + c;
#pragma unroll
    for (int ch = 0; ch < 4; ch++) {
      float4 v = *(const float4*)(smem + m0 * 512 + (((c + ch * 4) * 4) ^ ((m0 & 7) << 4)));
      *(float4*)(og + ch * 4) = v;
    }
  }
}

extern "C" void kernel_launch(void* const* d_in, const int* in_sizes, int n_in,
                              void* d_out, int out_size, void* d_ws, size_t ws_size,
                              hipStream_t stream) {
  const float* x  = (const float*)d_in[0];  // [B,256]
  const float* W1 = (const float*)d_in[1];  // [512,256]
  const float* b1 = (const float*)d_in[2];  // [512]
  const float* W2 = (const float*)d_in[3];  // [128,512]
  const float* b2 = (const float*)d_in[4];  // [128]
  float* o = (float*)d_out;

  const int B = in_sizes[0] / 256;

  u16* w1h = (u16*)d_ws;              // packed [16384][8]
  u16* w1l = w1h + 512 * 256;
  u16* w2h = w1l + 512 * 256;         // packed [8192][8]
  u16* w2l = w2h + 128 * 512;         // total 786432 B

  cvtW<<<96, 256, 0, stream>>>(W1, W2, w1h, w1l, w2h, w2l);
  hyper<<<B / 64, 512, 0, stream>>>(x, b1, b2, w1h, w1l, w2h, w2l, o);
}